// Round 14
// baseline (415.850 us; speedup 1.0000x reference)
//
#include <hip/hip_runtime.h>

#define DH 128

typedef __attribute__((ext_vector_type(8))) short short8;
typedef __attribute__((ext_vector_type(4))) float f32x4;

// ---------- helpers ----------
__device__ __forceinline__ float wave_sum(float v) {
    #pragma unroll
    for (int o = 32; o > 0; o >>= 1) v += __shfl_xor(v, o, 64);
    return v;
}

__device__ __forceinline__ void ln_pair(float v0, float v1, float& o0, float& o1) {
    float m = wave_sum(v0 + v1) * (1.f / 128.f);
    float d0 = v0 - m, d1 = v1 - m;
    float var = wave_sum(d0 * d0 + d1 * d1) * (1.f / 128.f);
    float inv = rsqrtf(var + 1e-5f);
    o0 = d0 * inv; o1 = d1 * inv;
}

__device__ __forceinline__ float elu(float x) { return x > 0.f ? x : expm1f(x); }

// fp32 -> bf16 round-to-nearest-even
__device__ __forceinline__ unsigned short f2bf(float f) {
    unsigned u = __float_as_uint(f);
    u += 0x7fffu + ((u >> 16) & 1u);
    return (unsigned short)(u >> 16);
}
__device__ __forceinline__ float bfl(unsigned u) { return __uint_as_float(u << 16); }
__device__ __forceinline__ float bfh(unsigned u) { return __uint_as_float(u & 0xffff0000u); }
__device__ __forceinline__ unsigned pack_bf2(float a, float b) {
    return (unsigned)f2bf(a) | ((unsigned)f2bf(b) << 16);
}
__device__ __forceinline__ short8 cvt8(float4 v0, float4 v1) {
    short8 o;
    o[0] = (short)f2bf(v0.x); o[1] = (short)f2bf(v0.y);
    o[2] = (short)f2bf(v0.z); o[3] = (short)f2bf(v0.w);
    o[4] = (short)f2bf(v1.x); o[5] = (short)f2bf(v1.y);
    o[6] = (short)f2bf(v1.z); o[7] = (short)f2bf(v1.w);
    return o;
}

// bijective XCD swizzle (m204)
__device__ __forceinline__ int xcd_work(int bid, int nwg) {
    int qc = nwg >> 3, rc = nwg & 7;
    int xcd = bid & 7, ix = bid >> 3;
    return (xcd < rc ? xcd * (qc + 1) : rc * (qc + 1) + (xcd - rc) * qc) + ix;
}

// barrier that does NOT drain vmcnt: LDS ops complete, global loads stay in flight
__device__ __forceinline__ void lgkm_barrier() {
    asm volatile("s_waitcnt lgkmcnt(0)" ::: "memory");
    __builtin_amdgcn_s_barrier();
    asm volatile("" ::: "memory");
}

// ---------- utility kernels ----------
__global__ void deg_count_k(const int* __restrict__ dst, int* __restrict__ deg, int E) {
    int e = blockIdx.x * 256 + threadIdx.x;
    if (e < E) atomicAdd(&deg[dst[e]], 1);
}

// ---------- parallel exclusive scan (3 kernels); also emits dinv ----------
__global__ __launch_bounds__(1024) void scan_part_k(const int* __restrict__ deg,
                                                    int* __restrict__ rowptr,
                                                    int* __restrict__ bsum,
                                                    float* __restrict__ dinv, int n)
{
    __shared__ int wsum[16];
    const int tid = threadIdx.x, lane = tid & 63, wid = tid >> 6;
    int i = blockIdx.x * 1024 + tid;
    int v = (i < n) ? deg[i] : 0;
    if (i < n) dinv[i] = rsqrtf((float)(v + 1));  // +1 self-loop
    int s = v;
    #pragma unroll
    for (int o = 1; o < 64; o <<= 1) {
        int t = __shfl_up(s, o, 64);
        if (lane >= o) s += t;
    }
    if (lane == 63) wsum[wid] = s;
    __syncthreads();
    if (tid < 16) {
        int ws = wsum[tid];
        #pragma unroll
        for (int o = 1; o < 16; o <<= 1) {
            int t = __shfl_up(ws, o, 64);
            if (tid >= o) ws += t;
        }
        wsum[tid] = ws;
    }
    __syncthreads();
    int excl = (wid ? wsum[wid - 1] : 0) + s - v;
    if (i < n) rowptr[i] = excl;
    if (tid == 0) bsum[blockIdx.x] = wsum[15];
}

__global__ void scan_top_k(int* __restrict__ bsum, int* __restrict__ rowptr_n, int nb) {
    int lane = threadIdx.x;  // blockDim = 64
    int carry = 0;
    for (int base = 0; base < nb; base += 64) {
        int i = base + lane;
        int v = (i < nb) ? bsum[i] : 0;
        int s = v;
        #pragma unroll
        for (int o = 1; o < 64; o <<= 1) {
            int t = __shfl_up(s, o, 64);
            if (lane >= o) s += t;
        }
        if (i < nb) bsum[i] = carry + s - v;
        carry += __shfl(s, 63, 64);
    }
    if (lane == 0) *rowptr_n = carry;
}

__global__ void scan_add_k(const int* __restrict__ bsum, int* __restrict__ rowptr,
                           int* __restrict__ cursor, int n)
{
    int i = blockIdx.x * 256 + threadIdx.x;
    if (i < n) {
        int v = rowptr[i] + bsum[i >> 10];
        rowptr[i] = v;
        cursor[i] = v;
    }
}

// XCD-bucketed CSR fill (see round-4 notes)
__global__ __launch_bounds__(256) void fill_xcd_k(
    const int* __restrict__ src, const int* __restrict__ dst,
    const float* __restrict__ dinv, int* __restrict__ cursor,
    int2* __restrict__ csr, int E, int n)
{
    const int g   = blockIdx.x & 7;
    const int j   = blockIdx.x >> 3;
    const int bpg = gridDim.x >> 3;
    const int per = (n + 7) >> 3;
    const int lo = g * per;
    const int hi = min(n, lo + per);
    for (int e = j * 256 + threadIdx.x; e < E; e += bpg * 256) {
        int d = dst[e];
        if (d >= lo && d < hi) {
            int s = src[e];
            float w = dinv[s] * dinv[d];
            int p = atomicAdd(&cursor[d], 1);
            csr[p] = make_int2(s, __float_as_int(w));
        }
    }
}

// repack all four W's fp32 -> bf16 fragment panels [kb][n][32] into one buffer;
// also zeroes deg (fused: saves one launch)
__global__ void repack_zero_k(const float* __restrict__ W1, const float* __restrict__ rW,
                              const float* __restrict__ W2, const float* __restrict__ mW1,
                              unsigned short* __restrict__ Wp, int* __restrict__ deg, int n)
{
    int idx = blockIdx.x * 256 + threadIdx.x;
    if (idx < n) deg[idx] = 0;
    if (idx >= 131072) return;
    const float* W; int base;
    if (idx < 49152)       { W = W1;  base = 0; }
    else if (idx < 98304)  { W = rW;  base = 49152; }
    else if (idx < 114688) { W = W2;  base = 98304; }
    else                   { W = mW1; base = 114688; }
    int l = idx - base;
    int kb = l >> 12, rem = l & 4095;
    int nn = rem >> 5, ki = rem & 31;
    Wp[idx] = f2bf(W[(kb * 32 + ki) * DH + nn]);
}

// ---------- GEMM1: K=384 in 6 slabs of BK=64 (round-9 variant, best total) ----------
__global__ __launch_bounds__(256, 2) void gemm1_k(
    const float* __restrict__ Af,
    const unsigned short* __restrict__ Bp1, const unsigned short* __restrict__ Bp2,
    const float* __restrict__ bb,
    unsigned short* __restrict__ outa, unsigned short* __restrict__ outb, int n)
{
    constexpr int K = 384, NT = 6;
    __shared__ __align__(16) unsigned short smem[24576];
    unsigned short* smB = smem + 16384;

    const int tid = threadIdx.x;
    const int wid = tid >> 6, lane = tid & 63;
    const int m16 = lane & 15, q = lane >> 4;

    const int work = xcd_work(blockIdx.x, gridDim.x);
    const int rblk = work >> 2;
    const int var  = work & 3;
    const int mat = var >> 1;
    const int c0  = (var & 1) * 64;
    const unsigned short* Bp = mat ? Bp2 : Bp1;
    unsigned short* outp = mat ? outb : outa;
    const float* bias = mat ? bb : nullptr;
    const long long rowbase = (long long)rblk * 128;

    const float* pA[4];
    unsigned short* dA[4];
    #pragma unroll
    for (int u = 0; u < 4; ++u) {
        int j = tid + 256 * u;
        int r = j >> 3, c = j & 7;
        long long gr = rowbase + r; if (gr > (long long)n - 1) gr = n - 1;
        pA[u] = Af + gr * K + c * 8;
        dA[u] = smem + r * 64 + ((c ^ (r & 7)) * 8);
    }
    const unsigned short* pB[2];
    unsigned short* dB[2];
    #pragma unroll
    for (int v = 0; v < 2; ++v) {
        int j = tid + 256 * v;
        int cl = j >> 3, c = j & 7;
        pB[v] = Bp + (c >> 2) * 4096 + (c0 + cl) * 32 + (c & 3) * 8;
        dB[v] = smB + cl * 64 + ((c ^ (cl & 7)) * 8);
    }

    float4 raf[2][4][2];
    short8 rbv[2][2];

    auto loadT = [&](int t, int buf) {
        #pragma unroll
        for (int u = 0; u < 4; ++u) {
            raf[buf][u][0] = *(const float4*)(pA[u] + t * 64);
            raf[buf][u][1] = *(const float4*)(pA[u] + t * 64 + 4);
        }
        #pragma unroll
        for (int v = 0; v < 2; ++v)
            rbv[buf][v] = *(const short8*)(pB[v] + t * 8192);
    };
    auto writeT = [&](int buf) {
        #pragma unroll
        for (int u = 0; u < 4; ++u)
            *(short8*)(dA[u] + buf * 8192) = cvt8(raf[buf][u][0], raf[buf][u][1]);
        #pragma unroll
        for (int v = 0; v < 2; ++v)
            *(short8*)(dB[v] + buf * 4096) = rbv[buf][v];
    };

    f32x4 acc[2][4];
    const f32x4 zero = {0.f, 0.f, 0.f, 0.f};
    #pragma unroll
    for (int mi = 0; mi < 2; ++mi)
        #pragma unroll
        for (int nj = 0; nj < 4; ++nj) acc[mi][nj] = zero;

    int sC[2];
    #pragma unroll
    for (int ks = 0; ks < 2; ++ks) sC[ks] = (((ks * 4 + q) ^ (m16 & 7)) * 8);
    const int arow = wid * 32 + m16;

    loadT(0, 0);
    loadT(1, 1);
    writeT(0);
    lgkm_barrier();

    #pragma unroll
    for (int t = 0; t < NT; ++t) {
        const int buf = t & 1;
        const unsigned short* a0 = smem + buf * 8192;
        const unsigned short* b0 = smB + buf * 4096;
        short8 af[2][2], bf[2][4];
        #pragma unroll
        for (int ks = 0; ks < 2; ++ks) {
            af[ks][0] = *(const short8*)(a0 + arow * 64 + sC[ks]);
            af[ks][1] = *(const short8*)(a0 + (arow + 16) * 64 + sC[ks]);
            #pragma unroll
            for (int nj = 0; nj < 4; ++nj)
                bf[ks][nj] = *(const short8*)(b0 + (nj * 16 + m16) * 64 + sC[ks]);
        }
        if (t + 2 < NT) loadT(t + 2, buf);
        if (t + 1 < NT) writeT(buf ^ 1);
        #pragma unroll
        for (int ks = 0; ks < 2; ++ks)
            #pragma unroll
            for (int nj = 0; nj < 4; ++nj) {
                acc[0][nj] = __builtin_amdgcn_mfma_f32_16x16x32_bf16(af[ks][0], bf[ks][nj], acc[0][nj], 0, 0, 0);
                acc[1][nj] = __builtin_amdgcn_mfma_f32_16x16x32_bf16(af[ks][1], bf[ks][nj], acc[1][nj], 0, 0, 0);
            }
        lgkm_barrier();
    }

    #pragma unroll
    for (int nj = 0; nj < 4; ++nj) {
        int cl = nj * 16 + m16;
        float bv = bias ? bias[c0 + cl] : 0.f;
        #pragma unroll
        for (int mi = 0; mi < 2; ++mi)
            #pragma unroll
            for (int r = 0; r < 4; ++r)
                smem[(wid * 32 + mi * 16 + q * 4 + r) * 72 + cl] = f2bf(acc[mi][nj][r] + bv);
    }
    __syncthreads();
    #pragma unroll
    for (int h = 0; h < 4; ++h) {
        int idx = tid + h * 256;
        int row = idx >> 3, c8 = idx & 7;
        long long grow = rowbase + row;
        if (grow < n)
            *(short8*)(outp + grow * DH + c0 + c8 * 8) = *(const short8*)(smem + row * 72 + c8 * 8);
    }
}

// ---------- GEMM K=128 (layer2): whole-panel LDS, single barrier ----------
__global__ __launch_bounds__(256, 3) void gemm_k128(
    const unsigned short* __restrict__ A,
    const unsigned short* __restrict__ Bp, const float* __restrict__ bias,
    unsigned short* __restrict__ outp, int n)
{
    __shared__ __align__(16) unsigned short smem[24576];
    unsigned short* smB = smem + 16384;

    const int tid = threadIdx.x;
    const int wid = tid >> 6, lane = tid & 63;
    const int m16 = lane & 15, q = lane >> 4;

    const int work = xcd_work(blockIdx.x, gridDim.x);
    const int rblk = work >> 1;
    const int c0 = (work & 1) * 64;
    const long long rowbase = (long long)rblk * 128;

    #pragma unroll
    for (int r = 0; r < 8; ++r) {
        int j = r * 256 + tid;
        int row = j >> 4, c16 = j & 15;
        long long grow = rowbase + row; if (grow > (long long)n - 1) grow = n - 1;
        *(short8*)(smem + row * 128 + ((c16 ^ (row & 15)) * 8)) =
            *(const short8*)(A + grow * 128 + c16 * 8);
    }
    #pragma unroll
    for (int r = 0; r < 4; ++r) {
        int j = r * 256 + tid;
        int kb = j >> 8, rem = j & 255;
        int cl = rem >> 2, qq = rem & 3;
        *(short8*)(smB + kb * 2048 + qq * 512 + cl * 8) =
            *(const short8*)(Bp + kb * 4096 + c0 * 32 + rem * 8);
    }
    __syncthreads();

    f32x4 acc[2][4];
    const f32x4 zero = {0.f, 0.f, 0.f, 0.f};
    #pragma unroll
    for (int mi = 0; mi < 2; ++mi)
        #pragma unroll
        for (int nj = 0; nj < 4; ++nj) acc[mi][nj] = zero;

    const int frow = wid * 32 + m16;
    #pragma unroll
    for (int kb = 0; kb < 4; ++kb) {
        short8 af0 = *(const short8*)(smem + frow * 128 + (((kb * 4 + q) ^ m16) * 8));
        short8 af1 = *(const short8*)(smem + (frow + 16) * 128 + (((kb * 4 + q) ^ m16) * 8));
        #pragma unroll
        for (int nj = 0; nj < 4; ++nj) {
            short8 bf = *(const short8*)(smB + kb * 2048 + q * 512 + (nj * 16 + m16) * 8);
            acc[0][nj] = __builtin_amdgcn_mfma_f32_16x16x32_bf16(af0, bf, acc[0][nj], 0, 0, 0);
            acc[1][nj] = __builtin_amdgcn_mfma_f32_16x16x32_bf16(af1, bf, acc[1][nj], 0, 0, 0);
        }
    }

    __syncthreads();
    #pragma unroll
    for (int nj = 0; nj < 4; ++nj) {
        int cl = nj * 16 + m16;
        float bv = bias ? bias[c0 + cl] : 0.f;
        #pragma unroll
        for (int mi = 0; mi < 2; ++mi)
            #pragma unroll
            for (int r = 0; r < 4; ++r)
                smem[(wid * 32 + mi * 16 + q * 4 + r) * 72 + cl] = f2bf(acc[mi][nj][r] + bv);
    }
    __syncthreads();
    #pragma unroll
    for (int h = 0; h < 4; ++h) {
        int idx = tid + h * 256;
        int row = idx >> 3, c8 = idx & 7;
        long long grow = rowbase + row;
        if (grow < n)
            *(short8*)(outp + grow * DH + c0 + c8 * 8) = *(const short8*)(smem + row * 72 + c8 * 8);
    }
}

// ---------- fused MLP gemm + head: z = elu(LN(h2@mW1+mb1)), out = softmax(z@mW2+mb2) ----------
// One block = full 128-row x 128-col z tile (acc[2][8]); z written to LDS as
// bf16 (identical RNE values to the old zraw buffer), then each wave runs the
// proven head_k row code from LDS. Removes one kernel launch + the 25.6MB
// zraw HBM round-trip. LDS 64KB staging, z reuses it (pitch 136 shorts).
__global__ __launch_bounds__(256, 2) void mlp_head_k(
    const unsigned short* __restrict__ A,      // h2 bf16 [n][128]
    const unsigned short* __restrict__ Bp,     // WpM [4][128][32]
    const float* __restrict__ mb1,
    const float* __restrict__ mg, const float* __restrict__ mbe,
    const float* __restrict__ mW2, const float* __restrict__ mb2,
    float* __restrict__ out, int n)
{
    __shared__ __align__(16) unsigned short smem[32768];  // A 16384 | B 16384
    unsigned short* smB = smem + 16384;

    const int tid = threadIdx.x;
    const int wid = tid >> 6, lane = tid & 63;
    const int m16 = lane & 15, q = lane >> 4;
    const long long rowbase = (long long)blockIdx.x * 128;

    // stage A (h2): [128 r][16 c16-chunks][8], chunk ^= row&15
    #pragma unroll
    for (int r = 0; r < 8; ++r) {
        int j = r * 256 + tid;
        int row = j >> 4, c16 = j & 15;
        long long grow = rowbase + row; if (grow > (long long)n - 1) grow = n - 1;
        *(short8*)(smem + row * 128 + ((c16 ^ (row & 15)) * 8)) =
            *(const short8*)(A + grow * 128 + c16 * 8);
    }
    // stage B (mW1 panel): linear copy, layout already [kb][cl][32]
    #pragma unroll
    for (int r = 0; r < 8; ++r) {
        int j = r * 256 + tid;
        *(short8*)(smB + j * 8) = *(const short8*)(Bp + j * 8);
    }
    __syncthreads();

    f32x4 acc[2][8];
    const f32x4 zero = {0.f, 0.f, 0.f, 0.f};
    #pragma unroll
    for (int mi = 0; mi < 2; ++mi)
        #pragma unroll
        for (int nj = 0; nj < 8; ++nj) acc[mi][nj] = zero;

    const int frow = wid * 32 + m16;
    #pragma unroll
    for (int kb = 0; kb < 4; ++kb) {
        short8 af0 = *(const short8*)(smem + frow * 128 + (((kb * 4 + q) ^ m16) * 8));
        short8 af1 = *(const short8*)(smem + (frow + 16) * 128 + (((kb * 4 + q) ^ m16) * 8));
        #pragma unroll
        for (int nj = 0; nj < 8; ++nj) {
            short8 bf = *(const short8*)(smB + kb * 4096 + (nj * 16 + m16) * 32 + q * 8);
            acc[0][nj] = __builtin_amdgcn_mfma_f32_16x16x32_bf16(af0, bf, acc[0][nj], 0, 0, 0);
            acc[1][nj] = __builtin_amdgcn_mfma_f32_16x16x32_bf16(af1, bf, acc[1][nj], 0, 0, 0);
        }
    }

    // z -> LDS (pitch 136 shorts; same bf16 RNE values as the old zraw buffer)
    __syncthreads();
    #pragma unroll
    for (int nj = 0; nj < 8; ++nj) {
        int col = nj * 16 + m16;
        float b = mb1[col];
        #pragma unroll
        for (int mi = 0; mi < 2; ++mi)
            #pragma unroll
            for (int r = 0; r < 4; ++r)
                smem[(wid * 32 + mi * 16 + q * 4 + r) * 136 + col] = f2bf(acc[mi][nj][r] + b);
    }
    __syncthreads();

    // head phase: wave wid handles rows wid*32 .. +31 (head_k code, LDS input)
    const int k = lane & 15, seg = lane >> 4;
    for (int rr = 0; rr < 32; ++rr) {
        int row = wid * 32 + rr;
        long long grow = rowbase + row;
        unsigned u = *(const unsigned*)(smem + row * 136 + 2 * lane);
        float o0, o1; ln_pair(bfl(u), bfh(u), o0, o1);
        float2 gv  = *(const float2*)(mg + 2 * lane);
        float2 bev = *(const float2*)(mbe + 2 * lane);
        float z0 = elu(o0 * gv.x + bev.x);
        float z1 = elu(o1 * gv.y + bev.y);
        float acch = 0.f;
        #pragma unroll
        for (int t = 0; t < 16; ++t) {
            int srcl = seg * 16 + t;
            float zz0 = __shfl(z0, srcl, 64);
            float zz1 = __shfl(z1, srcl, 64);
            int c = seg * 32 + 2 * t;
            acch = fmaf(zz0, mW2[c * 16 + k], acch);
            acch = fmaf(zz1, mW2[(c + 1) * 16 + k], acch);
        }
        acch += __shfl_xor(acch, 32, 64);
        acch += __shfl_xor(acch, 16, 64);
        float hk = acch + mb2[k];
        float mx = hk;
        #pragma unroll
        for (int o = 8; o > 0; o >>= 1) mx = fmaxf(mx, __shfl_xor(mx, o, 64));
        float e = expf(hk - mx);
        float s = e;
        #pragma unroll
        for (int o = 8; o > 0; o >>= 1) s += __shfl_xor(s, o, 64);
        if (lane < 16 && grow < n) out[grow * 16 + k] = e / s;
    }
}

// ---------- CSR gather: wave per row, 16 gathers in flight, scalar csr loads ----------
__device__ __forceinline__ void gather_row(
    const unsigned* __restrict__ hw, const int2* __restrict__ csr,
    int beg, int end, int lane, float& o0, float& o1)
{
    beg = __builtin_amdgcn_readfirstlane(beg);
    end = __builtin_amdgcn_readfirstlane(end);
    float a0 = 0.f, a1 = 0.f, b0 = 0.f, b1 = 0.f;
    float c0 = 0.f, c1 = 0.f, d0 = 0.f, d1 = 0.f;
    int p = beg;
    for (; p + 15 < end; p += 16) {
        int2 e[16];
        #pragma unroll
        for (int i = 0; i < 16; ++i) e[i] = csr[p + i];
        unsigned u[16];
        #pragma unroll
        for (int i = 0; i < 16; ++i) u[i] = hw[(long long)e[i].x * 64 + lane];
        #pragma unroll
        for (int i = 0; i < 16; ++i) {
            float w = __int_as_float(e[i].y);
            float lo = bfl(u[i]), hi = bfh(u[i]);
            if ((i & 3) == 0)      { a0 = fmaf(w, lo, a0); a1 = fmaf(w, hi, a1); }
            else if ((i & 3) == 1) { b0 = fmaf(w, lo, b0); b1 = fmaf(w, hi, b1); }
            else if ((i & 3) == 2) { c0 = fmaf(w, lo, c0); c1 = fmaf(w, hi, c1); }
            else                   { d0 = fmaf(w, lo, d0); d1 = fmaf(w, hi, d1); }
        }
    }
    for (; p + 3 < end; p += 4) {
        int2 e0 = csr[p], e1 = csr[p + 1], e2 = csr[p + 2], e3 = csr[p + 3];
        unsigned u0 = hw[(long long)e0.x * 64 + lane];
        unsigned u1 = hw[(long long)e1.x * 64 + lane];
        unsigned u2 = hw[(long long)e2.x * 64 + lane];
        unsigned u3 = hw[(long long)e3.x * 64 + lane];
        float w0 = __int_as_float(e0.y), w1 = __int_as_float(e1.y);
        float w2 = __int_as_float(e2.y), w3 = __int_as_float(e3.y);
        a0 = fmaf(w0, bfl(u0), a0);  a1 = fmaf(w0, bfh(u0), a1);
        b0 = fmaf(w1, bfl(u1), b0);  b1 = fmaf(w1, bfh(u1), b1);
        c0 = fmaf(w2, bfl(u2), c0);  c1 = fmaf(w2, bfh(u2), c1);
        d0 = fmaf(w3, bfl(u3), d0);  d1 = fmaf(w3, bfh(u3), d1);
    }
    for (; p < end; ++p) {
        int2 e0 = csr[p];
        unsigned u0 = hw[(long long)e0.x * 64 + lane];
        float w0 = __int_as_float(e0.y);
        a0 = fmaf(w0, bfl(u0), a0);
        a1 = fmaf(w0, bfh(u0), a1);
    }
    o0 = (a0 + b0) + (c0 + d0);
    o1 = (a1 + b1) + (c1 + d1);
}

// layer 1: h = elu(LN(gather + dinv^2*hw + b1)) + LN(proj)
__global__ __launch_bounds__(256) void gfuse1_k(
    const unsigned* __restrict__ hw, const unsigned* __restrict__ proj,
    const int* __restrict__ rowptr, const int2* __restrict__ csr,
    const float* __restrict__ dinv,
    const float* __restrict__ b1, const float* __restrict__ g1, const float* __restrict__ be1,
    const float* __restrict__ rg, const float* __restrict__ rbe,
    unsigned* __restrict__ hout, int n)
{
    int row = blockIdx.x * 4 + (threadIdx.x >> 6);
    if (row >= n) return;
    int lane = threadIdx.x & 63;
    float a0, a1;
    gather_row(hw, csr, rowptr[row], rowptr[row + 1], lane, a0, a1);
    long long off = (long long)row * 64;
    float di = dinv[row], sl = di * di;
    unsigned us = hw[off + lane];
    float2 bv  = *(const float2*)(b1 + 2 * lane);
    float2 gv  = *(const float2*)(g1 + 2 * lane);
    float2 bev = *(const float2*)(be1 + 2 * lane);
    float2 rgv = *(const float2*)(rg + 2 * lane);
    float2 rbv = *(const float2*)(rbe + 2 * lane);
    float v0 = a0 + sl * bfl(us) + bv.x;
    float v1 = a1 + sl * bfh(us) + bv.y;
    float o0, o1; ln_pair(v0, v1, o0, o1);
    float t0 = elu(o0 * gv.x + bev.x);
    float t1 = elu(o1 * gv.y + bev.y);
    unsigned up = proj[off + lane];
    float q0, q1; ln_pair(bfl(up), bfh(up), q0, q1);
    hout[off + lane] = pack_bf2(t0 + q0 * rgv.x + rbv.x, t1 + q1 * rgv.y + rbv.y);
}

// layer 2: h2 = elu(LN(gather + dinv^2*hw + b2)) + hprev
__global__ __launch_bounds__(256) void gfuse2_k(
    const unsigned* __restrict__ hw, const unsigned* __restrict__ hprev,
    const int* __restrict__ rowptr, const int2* __restrict__ csr,
    const float* __restrict__ dinv,
    const float* __restrict__ b2, const float* __restrict__ g2, const float* __restrict__ be2,
    unsigned* __restrict__ h2, int n)
{
    int row = blockIdx.x * 4 + (threadIdx.x >> 6);
    if (row >= n) return;
    int lane = threadIdx.x & 63;
    float a0, a1;
    gather_row(hw, csr, rowptr[row], rowptr[row + 1], lane, a0, a1);
    long long off = (long long)row * 64;
    float di = dinv[row], sl = di * di;
    unsigned us = hw[off + lane];
    float2 bv  = *(const float2*)(b2 + 2 * lane);
    float2 gv  = *(const float2*)(g2 + 2 * lane);
    float2 bev = *(const float2*)(be2 + 2 * lane);
    float v0 = a0 + sl * bfl(us) + bv.x;
    float v1 = a1 + sl * bfh(us) + bv.y;
    float o0, o1; ln_pair(v0, v1, o0, o1);
    float t0 = elu(o0 * gv.x + bev.x);
    float t1 = elu(o1 * gv.y + bev.y);
    unsigned uh = hprev[off + lane];
    h2[off + lane] = pack_bf2(t0 + bfl(uh), t1 + bfh(uh));
}

// ---------- launcher ----------
static inline size_t align16(size_t x) { return (x + 15) & ~(size_t)15; }

extern "C" void kernel_launch(void* const* d_in, const int* in_sizes, int n_in,
                              void* d_out, int out_size, void* d_ws, size_t ws_size,
                              hipStream_t stream)
{
    const float* x   = (const float*)d_in[0];
    const int*   ei  = (const int*)d_in[1];
    const float* W1  = (const float*)d_in[2];
    const float* b1  = (const float*)d_in[3];
    const float* g1  = (const float*)d_in[4];
    const float* be1 = (const float*)d_in[5];
    const float* W2  = (const float*)d_in[6];
    const float* b2  = (const float*)d_in[7];
    const float* g2  = (const float*)d_in[8];
    const float* be2 = (const float*)d_in[9];
    const float* rW  = (const float*)d_in[10];
    const float* rb  = (const float*)d_in[11];
    const float* rg  = (const float*)d_in[12];
    const float* rbe = (const float*)d_in[13];
    const float* mW1 = (const float*)d_in[14];
    const float* mb1 = (const float*)d_in[15];
    const float* mg  = (const float*)d_in[16];
    const float* mbe = (const float*)d_in[17];
    const float* mW2 = (const float*)d_in[18];
    const float* mb2 = (const float*)d_in[19];
    float* out = (float*)d_out;

    const int n = in_sizes[0] / 384;
    const int E = in_sizes[1] / 2;
    const int* src = ei;
    const int* dst = ei + E;

    char* w = (char*)d_ws;
    int* deg     = (int*)w;   w += align16((size_t)n * 4);
    int* rowptr  = (int*)w;   w += align16((size_t)(n + 1) * 4);
    int* cursor  = (int*)w;   w += align16((size_t)n * 4);
    float* dinv  = (float*)w; w += align16((size_t)n * 4);
    int* bsum    = (int*)w;   w += align16((size_t)1024 * 4);
    int2* csr    = (int2*)w;  w += align16((size_t)E * 8);
    unsigned short* hw1  = (unsigned short*)w; w += align16((size_t)n * DH * 2);
    unsigned short* proj = (unsigned short*)w; w += align16((size_t)n * DH * 2);
    unsigned short* hbuf = (unsigned short*)w; w += align16((size_t)n * DH * 2);
    unsigned short* Wp   = (unsigned short*)w; w += align16((size_t)131072 * 2);
    unsigned short* Wp1 = Wp;
    unsigned short* Wpr = Wp + 49152;
    unsigned short* Wp2 = Wp + 98304;
    unsigned short* WpM = Wp + 114688;
    unsigned short* hw2  = hw1;   // free after gfuse1
    unsigned short* h2   = proj;  // free after gfuse1

    int gE = (E + 255) / 256;
    int gN = (n + 255) / 256;
    int nb = (n + 1023) / 1024;
    int rblks = (n + 127) / 128;
    int gRow4 = (n + 3) / 4;

    // weight repack + deg zero (fused)
    repack_zero_k<<<512, 256, 0, stream>>>(W1, rW, W2, mW1, Wp, deg, n);

    // CSR build
    deg_count_k<<<gE, 256, 0, stream>>>(dst, deg, E);
    scan_part_k<<<nb, 1024, 0, stream>>>(deg, rowptr, bsum, dinv, n);
    scan_top_k<<<1, 64, 0, stream>>>(bsum, rowptr + n, nb);
    scan_add_k<<<gN, 256, 0, stream>>>(bsum, rowptr, cursor, n);
    fill_xcd_k<<<1024, 256, 0, stream>>>(src, dst, dinv, cursor, csr, E, n);

    // layer 1 (dual: hw1 = x@W1, proj = x@rW + rb)
    gemm1_k<<<rblks * 4, 256, 0, stream>>>(x, Wp1, Wpr, rb, hw1, proj, n);
    gfuse1_k<<<gRow4, 256, 0, stream>>>((unsigned*)hw1, (unsigned*)proj, rowptr, csr, dinv,
                                        b1, g1, be1, rg, rbe, (unsigned*)hbuf, n);

    // layer 2
    gemm_k128<<<rblks * 2, 256, 0, stream>>>(hbuf, Wp2, nullptr, hw2, n);
    gfuse2_k<<<gRow4, 256, 0, stream>>>((unsigned*)hw2, (unsigned*)hbuf, rowptr, csr, dinv,
                                        b2, g2, be2, (unsigned*)h2, n);

    // fused MLP head + softmax (removes head_k launch + zraw round-trip)
    mlp_head_k<<<rblks, 256, 0, stream>>>(h2, WpM, mb1, mg, mbe, mW2, mb2, out, n);
}

// Round 17
// 399.821 us; speedup vs baseline: 1.0401x; 1.0401x over previous
//
#include <hip/hip_runtime.h>

#define DH 128

typedef __attribute__((ext_vector_type(8))) short short8;
typedef __attribute__((ext_vector_type(4))) float f32x4;

// ---------- helpers ----------
__device__ __forceinline__ float wave_sum(float v) {
    #pragma unroll
    for (int o = 32; o > 0; o >>= 1) v += __shfl_xor(v, o, 64);
    return v;
}

__device__ __forceinline__ void ln_pair(float v0, float v1, float& o0, float& o1) {
    float m = wave_sum(v0 + v1) * (1.f / 128.f);
    float d0 = v0 - m, d1 = v1 - m;
    float var = wave_sum(d0 * d0 + d1 * d1) * (1.f / 128.f);
    float inv = rsqrtf(var + 1e-5f);
    o0 = d0 * inv; o1 = d1 * inv;
}

__device__ __forceinline__ float elu(float x) { return x > 0.f ? x : expm1f(x); }

// fp32 -> bf16 round-to-nearest-even
__device__ __forceinline__ unsigned short f2bf(float f) {
    unsigned u = __float_as_uint(f);
    u += 0x7fffu + ((u >> 16) & 1u);
    return (unsigned short)(u >> 16);
}
__device__ __forceinline__ float bfl(unsigned u) { return __uint_as_float(u << 16); }
__device__ __forceinline__ float bfh(unsigned u) { return __uint_as_float(u & 0xffff0000u); }
__device__ __forceinline__ unsigned pack_bf2(float a, float b) {
    return (unsigned)f2bf(a) | ((unsigned)f2bf(b) << 16);
}
__device__ __forceinline__ short8 cvt8(float4 v0, float4 v1) {
    short8 o;
    o[0] = (short)f2bf(v0.x); o[1] = (short)f2bf(v0.y);
    o[2] = (short)f2bf(v0.z); o[3] = (short)f2bf(v0.w);
    o[4] = (short)f2bf(v1.x); o[5] = (short)f2bf(v1.y);
    o[6] = (short)f2bf(v1.z); o[7] = (short)f2bf(v1.w);
    return o;
}

// bijective XCD swizzle (m204)
__device__ __forceinline__ int xcd_work(int bid, int nwg) {
    int qc = nwg >> 3, rc = nwg & 7;
    int xcd = bid & 7, ix = bid >> 3;
    return (xcd < rc ? xcd * (qc + 1) : rc * (qc + 1) + (xcd - rc) * qc) + ix;
}

// barrier that does NOT drain vmcnt: LDS ops complete, global loads stay in flight
__device__ __forceinline__ void lgkm_barrier() {
    asm volatile("s_waitcnt lgkmcnt(0)" ::: "memory");
    __builtin_amdgcn_s_barrier();
    asm volatile("" ::: "memory");
}

// ---------- utility kernels ----------
__global__ void deg_count_k(const int* __restrict__ dst, int* __restrict__ deg, int E) {
    int e = blockIdx.x * 256 + threadIdx.x;
    if (e < E) atomicAdd(&deg[dst[e]], 1);
}

// ---------- parallel exclusive scan (3 kernels); also emits dinv ----------
__global__ __launch_bounds__(1024) void scan_part_k(const int* __restrict__ deg,
                                                    int* __restrict__ rowptr,
                                                    int* __restrict__ bsum,
                                                    float* __restrict__ dinv, int n)
{
    __shared__ int wsum[16];
    const int tid = threadIdx.x, lane = tid & 63, wid = tid >> 6;
    int i = blockIdx.x * 1024 + tid;
    int v = (i < n) ? deg[i] : 0;
    if (i < n) dinv[i] = rsqrtf((float)(v + 1));  // +1 self-loop
    int s = v;
    #pragma unroll
    for (int o = 1; o < 64; o <<= 1) {
        int t = __shfl_up(s, o, 64);
        if (lane >= o) s += t;
    }
    if (lane == 63) wsum[wid] = s;
    __syncthreads();
    if (tid < 16) {
        int ws = wsum[tid];
        #pragma unroll
        for (int o = 1; o < 16; o <<= 1) {
            int t = __shfl_up(ws, o, 64);
            if (tid >= o) ws += t;
        }
        wsum[tid] = ws;
    }
    __syncthreads();
    int excl = (wid ? wsum[wid - 1] : 0) + s - v;
    if (i < n) rowptr[i] = excl;
    if (tid == 0) bsum[blockIdx.x] = wsum[15];
}

__global__ void scan_top_k(int* __restrict__ bsum, int* __restrict__ rowptr_n, int nb) {
    int lane = threadIdx.x;  // blockDim = 64
    int carry = 0;
    for (int base = 0; base < nb; base += 64) {
        int i = base + lane;
        int v = (i < nb) ? bsum[i] : 0;
        int s = v;
        #pragma unroll
        for (int o = 1; o < 64; o <<= 1) {
            int t = __shfl_up(s, o, 64);
            if (lane >= o) s += t;
        }
        if (i < nb) bsum[i] = carry + s - v;
        carry += __shfl(s, 63, 64);
    }
    if (lane == 0) *rowptr_n = carry;
}

__global__ void scan_add_k(const int* __restrict__ bsum, int* __restrict__ rowptr,
                           int* __restrict__ cursor, int n)
{
    int i = blockIdx.x * 256 + threadIdx.x;
    if (i < n) {
        int v = rowptr[i] + bsum[i >> 10];
        rowptr[i] = v;
        cursor[i] = v;
    }
}

// XCD-bucketed CSR fill (see round-4 notes)
__global__ __launch_bounds__(256) void fill_xcd_k(
    const int* __restrict__ src, const int* __restrict__ dst,
    const float* __restrict__ dinv, int* __restrict__ cursor,
    int2* __restrict__ csr, int E, int n)
{
    const int g   = blockIdx.x & 7;
    const int j   = blockIdx.x >> 3;
    const int bpg = gridDim.x >> 3;
    const int per = (n + 7) >> 3;
    const int lo = g * per;
    const int hi = min(n, lo + per);
    for (int e = j * 256 + threadIdx.x; e < E; e += bpg * 256) {
        int d = dst[e];
        if (d >= lo && d < hi) {
            int s = src[e];
            float w = dinv[s] * dinv[d];
            int p = atomicAdd(&cursor[d], 1);
            csr[p] = make_int2(s, __float_as_int(w));
        }
    }
}

// repack all four W's fp32 -> bf16 fragment panels [kb][n][32] into one buffer;
// also zeroes deg (fused: saves one launch)
__global__ void repack_zero_k(const float* __restrict__ W1, const float* __restrict__ rW,
                              const float* __restrict__ W2, const float* __restrict__ mW1,
                              unsigned short* __restrict__ Wp, int* __restrict__ deg, int n)
{
    int idx = blockIdx.x * 256 + threadIdx.x;
    if (idx < n) deg[idx] = 0;
    if (idx >= 131072) return;
    const float* W; int base;
    if (idx < 49152)       { W = W1;  base = 0; }
    else if (idx < 98304)  { W = rW;  base = 49152; }
    else if (idx < 114688) { W = W2;  base = 98304; }
    else                   { W = mW1; base = 114688; }
    int l = idx - base;
    int kb = l >> 12, rem = l & 4095;
    int nn = rem >> 5, ki = rem & 31;
    Wp[idx] = f2bf(W[(kb * 32 + ki) * DH + nn]);
}

// ---------- GEMM1: K=384 in 6 slabs of BK=64 (round-9 variant, best total) ----------
__global__ __launch_bounds__(256, 2) void gemm1_k(
    const float* __restrict__ Af,
    const unsigned short* __restrict__ Bp1, const unsigned short* __restrict__ Bp2,
    const float* __restrict__ bb,
    unsigned short* __restrict__ outa, unsigned short* __restrict__ outb, int n)
{
    constexpr int K = 384, NT = 6;
    __shared__ __align__(16) unsigned short smem[24576];
    unsigned short* smB = smem + 16384;

    const int tid = threadIdx.x;
    const int wid = tid >> 6, lane = tid & 63;
    const int m16 = lane & 15, q = lane >> 4;

    const int work = xcd_work(blockIdx.x, gridDim.x);
    const int rblk = work >> 2;
    const int var  = work & 3;
    const int mat = var >> 1;
    const int c0  = (var & 1) * 64;
    const unsigned short* Bp = mat ? Bp2 : Bp1;
    unsigned short* outp = mat ? outb : outa;
    const float* bias = mat ? bb : nullptr;
    const long long rowbase = (long long)rblk * 128;

    const float* pA[4];
    unsigned short* dA[4];
    #pragma unroll
    for (int u = 0; u < 4; ++u) {
        int j = tid + 256 * u;
        int r = j >> 3, c = j & 7;
        long long gr = rowbase + r; if (gr > (long long)n - 1) gr = n - 1;
        pA[u] = Af + gr * K + c * 8;
        dA[u] = smem + r * 64 + ((c ^ (r & 7)) * 8);
    }
    const unsigned short* pB[2];
    unsigned short* dB[2];
    #pragma unroll
    for (int v = 0; v < 2; ++v) {
        int j = tid + 256 * v;
        int cl = j >> 3, c = j & 7;
        pB[v] = Bp + (c >> 2) * 4096 + (c0 + cl) * 32 + (c & 3) * 8;
        dB[v] = smB + cl * 64 + ((c ^ (cl & 7)) * 8);
    }

    float4 raf[2][4][2];
    short8 rbv[2][2];

    auto loadT = [&](int t, int buf) {
        #pragma unroll
        for (int u = 0; u < 4; ++u) {
            raf[buf][u][0] = *(const float4*)(pA[u] + t * 64);
            raf[buf][u][1] = *(const float4*)(pA[u] + t * 64 + 4);
        }
        #pragma unroll
        for (int v = 0; v < 2; ++v)
            rbv[buf][v] = *(const short8*)(pB[v] + t * 8192);  // +2 panels/slab
    };
    auto writeT = [&](int buf) {
        #pragma unroll
        for (int u = 0; u < 4; ++u)
            *(short8*)(dA[u] + buf * 8192) = cvt8(raf[buf][u][0], raf[buf][u][1]);
        #pragma unroll
        for (int v = 0; v < 2; ++v)
            *(short8*)(dB[v] + buf * 4096) = rbv[buf][v];
    };

    f32x4 acc[2][4];
    const f32x4 zero = {0.f, 0.f, 0.f, 0.f};
    #pragma unroll
    for (int mi = 0; mi < 2; ++mi)
        #pragma unroll
        for (int nj = 0; nj < 4; ++nj) acc[mi][nj] = zero;

    int sC[2];
    #pragma unroll
    for (int ks = 0; ks < 2; ++ks) sC[ks] = (((ks * 4 + q) ^ (m16 & 7)) * 8);
    const int arow = wid * 32 + m16;

    loadT(0, 0);
    loadT(1, 1);
    writeT(0);
    lgkm_barrier();

    #pragma unroll
    for (int t = 0; t < NT; ++t) {
        const int buf = t & 1;
        const unsigned short* a0 = smem + buf * 8192;
        const unsigned short* b0 = smB + buf * 4096;
        short8 af[2][2], bf[2][4];
        #pragma unroll
        for (int ks = 0; ks < 2; ++ks) {
            af[ks][0] = *(const short8*)(a0 + arow * 64 + sC[ks]);
            af[ks][1] = *(const short8*)(a0 + (arow + 16) * 64 + sC[ks]);
            #pragma unroll
            for (int nj = 0; nj < 4; ++nj)
                bf[ks][nj] = *(const short8*)(b0 + (nj * 16 + m16) * 64 + sC[ks]);
        }
        if (t + 2 < NT) loadT(t + 2, buf);
        if (t + 1 < NT) writeT(buf ^ 1);
        #pragma unroll
        for (int ks = 0; ks < 2; ++ks)
            #pragma unroll
            for (int nj = 0; nj < 4; ++nj) {
                acc[0][nj] = __builtin_amdgcn_mfma_f32_16x16x32_bf16(af[ks][0], bf[ks][nj], acc[0][nj], 0, 0, 0);
                acc[1][nj] = __builtin_amdgcn_mfma_f32_16x16x32_bf16(af[ks][1], bf[ks][nj], acc[1][nj], 0, 0, 0);
            }
        lgkm_barrier();   // LDS visible; prefetch loads stay in flight
    }

    // ---- epilogue via smem: coalesced bf16 stores ----
    #pragma unroll
    for (int nj = 0; nj < 4; ++nj) {
        int cl = nj * 16 + m16;
        float bv = bias ? bias[c0 + cl] : 0.f;
        #pragma unroll
        for (int mi = 0; mi < 2; ++mi)
            #pragma unroll
            for (int r = 0; r < 4; ++r)
                smem[(wid * 32 + mi * 16 + q * 4 + r) * 72 + cl] = f2bf(acc[mi][nj][r] + bv);
    }
    __syncthreads();
    #pragma unroll
    for (int h = 0; h < 4; ++h) {
        int idx = tid + h * 256;
        int row = idx >> 3, c8 = idx & 7;
        long long grow = rowbase + row;
        if (grow < n)
            *(short8*)(outp + grow * DH + c0 + c8 * 8) = *(const short8*)(smem + row * 72 + c8 * 8);
    }
}

// ---------- GEMM K=128 (layer2 / MLP): whole-panel LDS, single barrier ----------
__global__ __launch_bounds__(256, 3) void gemm_k128(
    const unsigned short* __restrict__ A,
    const unsigned short* __restrict__ Bp, const float* __restrict__ bias,
    unsigned short* __restrict__ outp, int n)
{
    __shared__ __align__(16) unsigned short smem[24576];
    unsigned short* smB = smem + 16384;

    const int tid = threadIdx.x;
    const int wid = tid >> 6, lane = tid & 63;
    const int m16 = lane & 15, q = lane >> 4;

    const int work = xcd_work(blockIdx.x, gridDim.x);
    const int rblk = work >> 1;
    const int c0 = (work & 1) * 64;
    const long long rowbase = (long long)rblk * 128;

    #pragma unroll
    for (int r = 0; r < 8; ++r) {
        int j = r * 256 + tid;
        int row = j >> 4, c16 = j & 15;
        long long grow = rowbase + row; if (grow > (long long)n - 1) grow = n - 1;
        *(short8*)(smem + row * 128 + ((c16 ^ (row & 15)) * 8)) =
            *(const short8*)(A + grow * 128 + c16 * 8);
    }
    #pragma unroll
    for (int r = 0; r < 4; ++r) {
        int j = r * 256 + tid;
        int kb = j >> 8, rem = j & 255;
        int cl = rem >> 2, qq = rem & 3;
        *(short8*)(smB + kb * 2048 + qq * 512 + cl * 8) =
            *(const short8*)(Bp + kb * 4096 + c0 * 32 + rem * 8);
    }
    __syncthreads();

    f32x4 acc[2][4];
    const f32x4 zero = {0.f, 0.f, 0.f, 0.f};
    #pragma unroll
    for (int mi = 0; mi < 2; ++mi)
        #pragma unroll
        for (int nj = 0; nj < 4; ++nj) acc[mi][nj] = zero;

    const int frow = wid * 32 + m16;
    #pragma unroll
    for (int kb = 0; kb < 4; ++kb) {
        short8 af0 = *(const short8*)(smem + frow * 128 + (((kb * 4 + q) ^ m16) * 8));
        short8 af1 = *(const short8*)(smem + (frow + 16) * 128 + (((kb * 4 + q) ^ m16) * 8));
        #pragma unroll
        for (int nj = 0; nj < 4; ++nj) {
            short8 bf = *(const short8*)(smB + kb * 2048 + q * 512 + (nj * 16 + m16) * 8);
            acc[0][nj] = __builtin_amdgcn_mfma_f32_16x16x32_bf16(af0, bf, acc[0][nj], 0, 0, 0);
            acc[1][nj] = __builtin_amdgcn_mfma_f32_16x16x32_bf16(af1, bf, acc[1][nj], 0, 0, 0);
        }
    }

    __syncthreads();
    #pragma unroll
    for (int nj = 0; nj < 4; ++nj) {
        int cl = nj * 16 + m16;
        float bv = bias ? bias[c0 + cl] : 0.f;
        #pragma unroll
        for (int mi = 0; mi < 2; ++mi)
            #pragma unroll
            for (int r = 0; r < 4; ++r)
                smem[(wid * 32 + mi * 16 + q * 4 + r) * 72 + cl] = f2bf(acc[mi][nj][r] + bv);
    }
    __syncthreads();
    #pragma unroll
    for (int h = 0; h < 4; ++h) {
        int idx = tid + h * 256;
        int row = idx >> 3, c8 = idx & 7;
        long long grow = rowbase + row;
        if (grow < n)
            *(short8*)(outp + grow * DH + c0 + c8 * 8) = *(const short8*)(smem + row * 72 + c8 * 8);
    }
}

// ---------- CSR gather: wave per row, 16 gathers in flight, scalar csr loads ----------
__device__ __forceinline__ void gather_row(
    const unsigned* __restrict__ hw, const int2* __restrict__ csr,
    int beg, int end, int lane, float& o0, float& o1)
{
    beg = __builtin_amdgcn_readfirstlane(beg);
    end = __builtin_amdgcn_readfirstlane(end);
    float a0 = 0.f, a1 = 0.f, b0 = 0.f, b1 = 0.f;
    float c0 = 0.f, c1 = 0.f, d0 = 0.f, d1 = 0.f;
    int p = beg;
    for (; p + 15 < end; p += 16) {
        int2 e[16];
        #pragma unroll
        for (int i = 0; i < 16; ++i) e[i] = csr[p + i];
        unsigned u[16];
        #pragma unroll
        for (int i = 0; i < 16; ++i) u[i] = hw[(long long)e[i].x * 64 + lane];
        #pragma unroll
        for (int i = 0; i < 16; ++i) {
            float w = __int_as_float(e[i].y);
            float lo = bfl(u[i]), hi = bfh(u[i]);
            if ((i & 3) == 0)      { a0 = fmaf(w, lo, a0); a1 = fmaf(w, hi, a1); }
            else if ((i & 3) == 1) { b0 = fmaf(w, lo, b0); b1 = fmaf(w, hi, b1); }
            else if ((i & 3) == 2) { c0 = fmaf(w, lo, c0); c1 = fmaf(w, hi, c1); }
            else                   { d0 = fmaf(w, lo, d0); d1 = fmaf(w, hi, d1); }
        }
    }
    for (; p + 3 < end; p += 4) {
        int2 e0 = csr[p], e1 = csr[p + 1], e2 = csr[p + 2], e3 = csr[p + 3];
        unsigned u0 = hw[(long long)e0.x * 64 + lane];
        unsigned u1 = hw[(long long)e1.x * 64 + lane];
        unsigned u2 = hw[(long long)e2.x * 64 + lane];
        unsigned u3 = hw[(long long)e3.x * 64 + lane];
        float w0 = __int_as_float(e0.y), w1 = __int_as_float(e1.y);
        float w2 = __int_as_float(e2.y), w3 = __int_as_float(e3.y);
        a0 = fmaf(w0, bfl(u0), a0);  a1 = fmaf(w0, bfh(u0), a1);
        b0 = fmaf(w1, bfl(u1), b0);  b1 = fmaf(w1, bfh(u1), b1);
        c0 = fmaf(w2, bfl(u2), c0);  c1 = fmaf(w2, bfh(u2), c1);
        d0 = fmaf(w3, bfl(u3), d0);  d1 = fmaf(w3, bfh(u3), d1);
    }
    for (; p < end; ++p) {
        int2 e0 = csr[p];
        unsigned u0 = hw[(long long)e0.x * 64 + lane];
        float w0 = __int_as_float(e0.y);
        a0 = fmaf(w0, bfl(u0), a0);
        a1 = fmaf(w0, bfh(u0), a1);
    }
    o0 = (a0 + b0) + (c0 + d0);
    o1 = (a1 + b1) + (c1 + d1);
}

// layer 1: h = elu(LN(gather + dinv^2*hw + b1)) + LN(proj)
__global__ __launch_bounds__(256) void gfuse1_k(
    const unsigned* __restrict__ hw, const unsigned* __restrict__ proj,
    const int* __restrict__ rowptr, const int2* __restrict__ csr,
    const float* __restrict__ dinv,
    const float* __restrict__ b1, const float* __restrict__ g1, const float* __restrict__ be1,
    const float* __restrict__ rg, const float* __restrict__ rbe,
    unsigned* __restrict__ hout, int n)
{
    int row = blockIdx.x * 4 + (threadIdx.x >> 6);
    if (row >= n) return;
    int lane = threadIdx.x & 63;
    float a0, a1;
    gather_row(hw, csr, rowptr[row], rowptr[row + 1], lane, a0, a1);
    long long off = (long long)row * 64;
    float di = dinv[row], sl = di * di;
    unsigned us = hw[off + lane];
    float2 bv  = *(const float2*)(b1 + 2 * lane);
    float2 gv  = *(const float2*)(g1 + 2 * lane);
    float2 bev = *(const float2*)(be1 + 2 * lane);
    float2 rgv = *(const float2*)(rg + 2 * lane);
    float2 rbv = *(const float2*)(rbe + 2 * lane);
    float v0 = a0 + sl * bfl(us) + bv.x;
    float v1 = a1 + sl * bfh(us) + bv.y;
    float o0, o1; ln_pair(v0, v1, o0, o1);
    float t0 = elu(o0 * gv.x + bev.x);
    float t1 = elu(o1 * gv.y + bev.y);
    unsigned up = proj[off + lane];
    float q0, q1; ln_pair(bfl(up), bfh(up), q0, q1);
    hout[off + lane] = pack_bf2(t0 + q0 * rgv.x + rbv.x, t1 + q1 * rgv.y + rbv.y);
}

// layer 2: h2 = elu(LN(gather + dinv^2*hw + b2)) + hprev
__global__ __launch_bounds__(256) void gfuse2_k(
    const unsigned* __restrict__ hw, const unsigned* __restrict__ hprev,
    const int* __restrict__ rowptr, const int2* __restrict__ csr,
    const float* __restrict__ dinv,
    const float* __restrict__ b2, const float* __restrict__ g2, const float* __restrict__ be2,
    unsigned* __restrict__ h2, int n)
{
    int row = blockIdx.x * 4 + (threadIdx.x >> 6);
    if (row >= n) return;
    int lane = threadIdx.x & 63;
    float a0, a1;
    gather_row(hw, csr, rowptr[row], rowptr[row + 1], lane, a0, a1);
    long long off = (long long)row * 64;
    float di = dinv[row], sl = di * di;
    unsigned us = hw[off + lane];
    float2 bv  = *(const float2*)(b2 + 2 * lane);
    float2 gv  = *(const float2*)(g2 + 2 * lane);
    float2 bev = *(const float2*)(be2 + 2 * lane);
    float v0 = a0 + sl * bfl(us) + bv.x;
    float v1 = a1 + sl * bfh(us) + bv.y;
    float o0, o1; ln_pair(v0, v1, o0, o1);
    float t0 = elu(o0 * gv.x + bev.x);
    float t1 = elu(o1 * gv.y + bev.y);
    unsigned uh = hprev[off + lane];
    h2[off + lane] = pack_bf2(t0 + bfl(uh), t1 + bfh(uh));
}

// ---------- head: LN+ELU on zraw, z @ mW2 + mb2, softmax K=16 (fused) ----------
__global__ __launch_bounds__(256) void head_k(
    const unsigned* __restrict__ zraw, const float* __restrict__ g, const float* __restrict__ be,
    const float* __restrict__ mW2, const float* __restrict__ mb2,
    float* __restrict__ out, int n)
{
    int row = blockIdx.x * 4 + (threadIdx.x >> 6);
    if (row >= n) return;
    int lane = threadIdx.x & 63;
    unsigned u = zraw[(long long)row * 64 + lane];
    float o0, o1; ln_pair(bfl(u), bfh(u), o0, o1);
    float2 gv  = *(const float2*)(g + 2 * lane);
    float2 bev = *(const float2*)(be + 2 * lane);
    float z0 = elu(o0 * gv.x + bev.x);
    float z1 = elu(o1 * gv.y + bev.y);
    int k = lane & 15, seg = lane >> 4;
    float acc = 0.f;
    #pragma unroll
    for (int t = 0; t < 16; ++t) {
        int srcl = seg * 16 + t;
        float zz0 = __shfl(z0, srcl, 64);
        float zz1 = __shfl(z1, srcl, 64);
        int c = seg * 32 + 2 * t;
        acc = fmaf(zz0, mW2[c * 16 + k], acc);
        acc = fmaf(zz1, mW2[(c + 1) * 16 + k], acc);
    }
    acc += __shfl_xor(acc, 32, 64);
    acc += __shfl_xor(acc, 16, 64);
    float hk = acc + mb2[k];
    float mx = hk;
    #pragma unroll
    for (int o = 8; o > 0; o >>= 1) mx = fmaxf(mx, __shfl_xor(mx, o, 64));
    float e = expf(hk - mx);
    float s = e;
    #pragma unroll
    for (int o = 8; o > 0; o >>= 1) s += __shfl_xor(s, o, 64);
    if (lane < 16) out[(long long)row * 16 + k] = e / s;
}

// ---------- launcher ----------
static inline size_t align16(size_t x) { return (x + 15) & ~(size_t)15; }

extern "C" void kernel_launch(void* const* d_in, const int* in_sizes, int n_in,
                              void* d_out, int out_size, void* d_ws, size_t ws_size,
                              hipStream_t stream)
{
    const float* x   = (const float*)d_in[0];
    const int*   ei  = (const int*)d_in[1];
    const float* W1  = (const float*)d_in[2];
    const float* b1  = (const float*)d_in[3];
    const float* g1  = (const float*)d_in[4];
    const float* be1 = (const float*)d_in[5];
    const float* W2  = (const float*)d_in[6];
    const float* b2  = (const float*)d_in[7];
    const float* g2  = (const float*)d_in[8];
    const float* be2 = (const float*)d_in[9];
    const float* rW  = (const float*)d_in[10];
    const float* rb  = (const float*)d_in[11];
    const float* rg  = (const float*)d_in[12];
    const float* rbe = (const float*)d_in[13];
    const float* mW1 = (const float*)d_in[14];
    const float* mb1 = (const float*)d_in[15];
    const float* mg  = (const float*)d_in[16];
    const float* mbe = (const float*)d_in[17];
    const float* mW2 = (const float*)d_in[18];
    const float* mb2 = (const float*)d_in[19];
    float* out = (float*)d_out;

    const int n = in_sizes[0] / 384;
    const int E = in_sizes[1] / 2;
    const int* src = ei;
    const int* dst = ei + E;

    char* w = (char*)d_ws;
    int* deg     = (int*)w;   w += align16((size_t)n * 4);
    int* rowptr  = (int*)w;   w += align16((size_t)(n + 1) * 4);
    int* cursor  = (int*)w;   w += align16((size_t)n * 4);
    float* dinv  = (float*)w; w += align16((size_t)n * 4);
    int* bsum    = (int*)w;   w += align16((size_t)1024 * 4);
    int2* csr    = (int2*)w;  w += align16((size_t)E * 8);
    unsigned short* hw1  = (unsigned short*)w; w += align16((size_t)n * DH * 2);
    unsigned short* proj = (unsigned short*)w; w += align16((size_t)n * DH * 2);
    unsigned short* hbuf = (unsigned short*)w; w += align16((size_t)n * DH * 2);
    unsigned short* Wp   = (unsigned short*)w; w += align16((size_t)131072 * 2);
    unsigned short* Wp1 = Wp;
    unsigned short* Wpr = Wp + 49152;
    unsigned short* Wp2 = Wp + 98304;
    unsigned short* WpM = Wp + 114688;
    unsigned short* hw2  = hw1;   // free after gfuse1
    unsigned short* h2   = proj;  // free after gfuse1
    unsigned short* zraw = hbuf;  // free after gfuse2

    int gE = (E + 255) / 256;
    int gN = (n + 255) / 256;
    int nb = (n + 1023) / 1024;
    int rblks = (n + 127) / 128;
    int gRow4 = (n + 3) / 4;

    // weight repack + deg zero (fused)
    repack_zero_k<<<512, 256, 0, stream>>>(W1, rW, W2, mW1, Wp, deg, n);

    // CSR build
    deg_count_k<<<gE, 256, 0, stream>>>(dst, deg, E);
    scan_part_k<<<nb, 1024, 0, stream>>>(deg, rowptr, bsum, dinv, n);
    scan_top_k<<<1, 64, 0, stream>>>(bsum, rowptr + n, nb);
    scan_add_k<<<gN, 256, 0, stream>>>(bsum, rowptr, cursor, n);
    fill_xcd_k<<<1024, 256, 0, stream>>>(src, dst, dinv, cursor, csr, E, n);

    // layer 1 (dual: hw1 = x@W1, proj = x@rW + rb); fp32 A converted at staging
    gemm1_k<<<rblks * 4, 256, 0, stream>>>(x, Wp1, Wpr, rb, hw1, proj, n);
    gfuse1_k<<<gRow4, 256, 0, stream>>>((unsigned*)hw1, (unsigned*)proj, rowptr, csr, dinv,
                                        b1, g1, be1, rg, rbe, (unsigned*)hbuf, n);

    // layer 2
    gemm_k128<<<rblks * 2, 256, 0, stream>>>(hbuf, Wp2, nullptr, hw2, n);
    gfuse2_k<<<gRow4, 256, 0, stream>>>((unsigned*)hw2, (unsigned*)hbuf, rowptr, csr, dinv,
                                        b2, g2, be2, (unsigned*)h2, n);

    // MLP head + softmax
    gemm_k128<<<rblks * 2, 256, 0, stream>>>(h2, WpM, mb1, zraw, n);
    head_k<<<gRow4, 256, 0, stream>>>((unsigned*)zraw, mg, mbe, mW2, mb2, out, n);
}